// Round 8
// baseline (82.329 us; speedup 1.0000x reference)
//
#include <hip/hip_runtime.h>
#include <cstdint>
#include <cstddef>

// Problem constants
#define NB 2
#define NF 8
#define NS 4
#define NK 90      // real K (dirs per shell)
#define NP 642     // grid vertices
#define NXYZ 1728  // 12*12*12
#define MT 64      // p-tile (prep layout)
#define PTILES 11  // ceil(642/64)
#define NG 108     // xyz 16-groups (1728/16)
#define XT_TASKS (64 * NG * 3)          // 20736 x-fragment blocks (1 KB each)
#define WT_TASKS (NS * PTILES * 4 * 3)  // 528 W-fragment blocks

typedef __attribute__((ext_vector_type(8))) __bf16 bf16x8;
typedef __attribute__((ext_vector_type(4))) float f32x4;
typedef __attribute__((ext_vector_type(4))) uint32_t u32x4;

// RNE pack of two f32 -> u32 holding 2 bf16
__device__ __forceinline__ uint32_t pack2bf(float a, float b) {
    uint32_t ua = __builtin_bit_cast(uint32_t, a);
    uint32_t ub = __builtin_bit_cast(uint32_t, b);
    ua += 0x7FFFu + ((ua >> 16) & 1u);
    ub += 0x7FFFu + ((ub >> 16) & 1u);
    return (ua >> 16) | (ub & 0xFFFF0000u);
}

// ============ Kernel 1: pack x and W into MFMA-fragment-order bf16 blocks.
// (unchanged from R5/R7 — layout compatible with 32-p sub-tiling since
//  W frag (pt,ni,kk) offset = (s*132 + sub*6 + nj*3 + kk) KB with
//  sub = pt*2 + (ni>>1), nj = ni&1.)
__global__ __launch_bounds__(256) void prep_frag(
    const float* __restrict__ x, const float* __restrict__ Wm,
    uint32_t* __restrict__ ws)
{
    const int tid  = (int)threadIdx.x;
    const int lane = tid & 63;
    const int lr = lane & 15, lg = lane >> 4;
    const int task = (int)blockIdx.x * 4 + (tid >> 6);

    float v[8];
    if (task < XT_TASKS) {
        int t = task;
        const int kk = t % 3;   t /= 3;
        const int g  = t % NG;  t /= NG;
        const int e  = t;                  // 0..63
        const int s = e & 3, bf = e >> 2;
        const float* src = x + (size_t)bf * (NS * NK * NXYZ)
                             + (size_t)s * (NK * NXYZ) + g * 16 + lr;
        #pragma unroll
        for (int j = 0; j < 8; ++j) {
            const int k = kk * 32 + lg * 8 + j;
            v[j] = (k < NK) ? src[(size_t)k * NXYZ] : 0.f;
        }
    } else {
        int t = task - XT_TASKS;
        const int kk = t % 3;      t /= 3;
        const int ni = t % 4;      t /= 4;
        const int pt = t % PTILES; t /= PTILES;
        const int s  = t;                  // 0..3
        const int p = pt * MT + ni * 16 + lr;
        const float* src = Wm + (size_t)s * (NK * NP) + p;
        #pragma unroll
        for (int j = 0; j < 8; ++j) {
            const int k = kk * 32 + lg * 8 + j;
            v[j] = (k < NK && p < NP) ? src[(size_t)k * NP] : 0.f;
        }
    }
    u32x4 u;
    u.x = pack2bf(v[0], v[1]);
    u.y = pack2bf(v[2], v[3]);
    u.z = pack2bf(v[4], v[5]);
    u.w = pack2bf(v[6], v[7]);
    *(u32x4*)((char*)ws + (size_t)task * 1024 + lane * 16) = u;
}

// ============ Kernel 2: looped-wave GEMM at full occupancy. Wave = (e,n32):
// B-frags (32 xyz) in regs for the whole run; loop 21 sub-tiles of 32 p with
// ping-ponged A prefetch (6 frags ahead) and ping-ponged accumulators.
// Stores issue every iteration -> continuous write stream per wave.
#define COMPUTE_SUB(ACC, ASET)                                            \
    _Pragma("unroll")                                                     \
    for (int kk = 0; kk < 3; ++kk)                                        \
        _Pragma("unroll")                                                 \
        for (int mi = 0; mi < 2; ++mi)                                    \
            _Pragma("unroll")                                             \
            for (int nj = 0; nj < 2; ++nj)                                \
                ACC[mi][nj] = __builtin_amdgcn_mfma_f32_16x16x32_bf16(    \
                    B[mi * 3 + kk], ASET[nj * 3 + kk],                    \
                    kk ? ACC[mi][nj] : (f32x4){0.f, 0.f, 0.f, 0.f},       \
                    0, 0, 0);

#define STORE_SUB(ACC, SUB)                                               \
    {                                                                     \
        float* dst0 = ybase + (size_t)((SUB) * 32) * NXYZ;                \
        _Pragma("unroll")                                                 \
        for (int nj = 0; nj < 2; ++nj) {                                  \
            float* dst = dst0 + (size_t)(nj * 16) * NXYZ;                 \
            *(f32x4*)dst = ACC[0][nj];                                    \
            *(f32x4*)(dst + 16) = ACC[1][nj];                             \
        }                                                                 \
    }

__global__ __launch_bounds__(256, 4) void gemm_pipe(
    const uint32_t* __restrict__ ws, float* __restrict__ y)
{
    const int tid  = (int)threadIdx.x;
    const int lane = tid & 63;
    const int lr = lane & 15, lg = lane >> 4;
    int t = (int)blockIdx.x * 4 + (tid >> 6);
    const int n32 = t % 54;  t /= 54;
    const int e = t;                        // 0..63
    const int s = e & 3, bfi = e >> 2;
    const int b = bfi >> 3, f = bfi & 7;

    const char* lbase = (const char*)ws + (size_t)lane * 16;
    const char* xb = lbase + (size_t)((e * NG + n32 * 2) * 3) * 1024;
    const char* ab = lbase + (size_t)(XT_TASKS + s * 132) * 1024;
    // A frag (sub, nj, kk) at ab + (sub*6 + nj*3 + kk) KB, sub in [0,21)

    bf16x8 B[6];  // B[mi*3+kk], loaded ONCE (x_t read exactly once total)
    #pragma unroll
    for (int i = 0; i < 6; ++i) B[i] = *(const bf16x8*)(xb + i * 1024);

    bf16x8 A0[6], A1[6];
    #pragma unroll
    for (int i = 0; i < 6; ++i) A0[i] = *(const bf16x8*)(ab + i * 1024);  // sub 0

    const size_t chan = (size_t)b * (NS * NF) + (size_t)s * NF + f;
    float* ybase = y + chan * ((size_t)NP * NXYZ) + (size_t)lr * NXYZ
                     + n32 * 32 + lg * 4;
    // store addr: ybase + (sub*32 + nj*16)*NXYZ (+16 for mi=1); p = sub*32+nj*16+lr

    f32x4 accE[2][2], accO[2][2];

    #pragma unroll 1
    for (int j = 0; j < 10; ++j) {
        const int se = 2 * j, so = se + 1;
        // prefetch A(so) into A1 (latency hidden under compute/store of se)
        {
            const char* an = ab + (size_t)(so * 6) * 1024;
            #pragma unroll
            for (int i = 0; i < 6; ++i) A1[i] = *(const bf16x8*)(an + i * 1024);
        }
        COMPUTE_SUB(accE, A0)     // sub = se
        STORE_SUB(accE, se)
        // prefetch A(so+1) into A0 (j=9 loads sub 20 for the epilogue)
        {
            const char* an = ab + (size_t)((so + 1) * 6) * 1024;
            #pragma unroll
            for (int i = 0; i < 6; ++i) A0[i] = *(const bf16x8*)(an + i * 1024);
        }
        COMPUTE_SUB(accO, A1)     // sub = so
        STORE_SUB(accO, so)
    }

    // Epilogue sub = 20 (p 640..671): only nj=0, lr<2 valid (frags zero-padded).
    COMPUTE_SUB(accE, A0)
    if (lr < 2) {
        float* dst = ybase + (size_t)(20 * 32) * NXYZ;
        *(f32x4*)dst = accE[0][0];
        *(f32x4*)(dst + 16) = accE[1][0];
    }
}

// ============ Fallback (round-3 structure) if ws too small ================
#define NT 96
#define NTILES 18
#define KP 96
#define ROWB (KP * 2)

__global__ __launch_bounds__(192, 4) void interp_fallback(
    const float* __restrict__ x, const float* __restrict__ Wm,
    float* __restrict__ y)
{
    __shared__ __align__(16) char As[MT * ROWB];
    __shared__ __align__(16) char Bs[NT * ROWB];

    int blk = (int)blockIdx.x;
    const int nt = blk % NTILES; blk /= NTILES;
    const int f  = blk % NF;     blk /= NF;
    const int s  = blk % NS;     blk /= NS;
    const int b  = blk;
    const int tid = (int)threadIdx.x;
    const int n0 = nt * NT;

    {
        const int c  = tid % NT;
        const int kh = tid / NT;
        const float* xp = x + (((size_t)b * NF + f) * (NS * NK) + (size_t)s * NK) * NXYZ
                            + n0 + c;
        const int cs = (c & 7) << 4;
        #pragma unroll
        for (int kk = 0; kk < 48; kk += 8) {
            const int kb = kh * 48 + kk;
            float v[8];
            #pragma unroll
            for (int j = 0; j < 8; ++j) {
                const int k = kb + j;
                v[j] = (k < NK) ? xp[(size_t)k * NXYZ] : 0.f;
            }
            u32x4 u;
            u.x = pack2bf(v[0], v[1]); u.y = pack2bf(v[2], v[3]);
            u.z = pack2bf(v[4], v[5]); u.w = pack2bf(v[6], v[7]);
            *(u32x4*)(Bs + ((c * ROWB + kb * 2) ^ cs)) = u;
        }
    }

    const int lane = tid & 63;
    const int w  = tid / 64;
    const int lr = lane & 15;
    const int lg = lane >> 4;
    const int ls = (lr & 7) << 4;
    const size_t chan = (size_t)b * (NS * NF) + (size_t)s * NF + f;
    float* ybase = y + chan * ((size_t)NP * NXYZ);
    const int xyzbase = n0 + w * 32 + lg * 4;
    const int ar = tid & 63;
    const int akc = tid >> 6;
    const int ars = (ar & 7) << 4;

    for (int pt = 0; pt < PTILES; ++pt) {
        const int p0 = pt * MT;
        __syncthreads();
        {
            const int p = p0 + ar;
            const bool pv = (p < NP);
            const float* wp = Wm + (size_t)s * NK * NP + p;
            #pragma unroll
            for (int kk = 0; kk < 32; kk += 8) {
                const int kb = akc * 32 + kk;
                float v[8];
                #pragma unroll
                for (int j = 0; j < 8; ++j) {
                    const int k = kb + j;
                    v[j] = (pv && (k < NK)) ? wp[(size_t)k * NP] : 0.f;
                }
                u32x4 u;
                u.x = pack2bf(v[0], v[1]); u.y = pack2bf(v[2], v[3]);
                u.z = pack2bf(v[4], v[5]); u.w = pack2bf(v[6], v[7]);
                *(u32x4*)(As + ((ar * ROWB + kb * 2) ^ ars)) = u;
            }
        }
        __syncthreads();

        f32x4 acc[2][4];
        #pragma unroll
        for (int mi = 0; mi < 2; ++mi)
            #pragma unroll
            for (int ni = 0; ni < 4; ++ni)
                acc[mi][ni] = (f32x4){0.f, 0.f, 0.f, 0.f};

        #pragma unroll
        for (int kk = 0; kk < 3; ++kk) {
            const int kbyte = kk * 64 + lg * 16;
            bf16x8 bxyz[2], ap[4];
            #pragma unroll
            for (int mi = 0; mi < 2; ++mi) {
                const int row = w * 32 + mi * 16 + lr;
                bxyz[mi] = *(const bf16x8*)(Bs + ((row * ROWB + kbyte) ^ ls));
            }
            #pragma unroll
            for (int ni = 0; ni < 4; ++ni) {
                const int row = ni * 16 + lr;
                ap[ni] = *(const bf16x8*)(As + ((row * ROWB + kbyte) ^ ls));
            }
            #pragma unroll
            for (int mi = 0; mi < 2; ++mi)
                #pragma unroll
                for (int ni = 0; ni < 4; ++ni)
                    acc[mi][ni] = __builtin_amdgcn_mfma_f32_16x16x32_bf16(
                        bxyz[mi], ap[ni], acc[mi][ni], 0, 0, 0);
        }

        #pragma unroll
        for (int ni = 0; ni < 4; ++ni) {
            const int p = p0 + ni * 16 + lr;
            if (p < NP) {
                float* dst = ybase + (size_t)p * NXYZ + xyzbase;
                *(f32x4*)dst = acc[0][ni];
                *(f32x4*)(dst + 16) = acc[1][ni];
            }
        }
    }
}

extern "C" void kernel_launch(void* const* d_in, const int* in_sizes, int n_in,
                              void* d_out, int out_size, void* d_ws, size_t ws_size,
                              hipStream_t stream) {
    (void)in_sizes; (void)n_in; (void)out_size;
    const float* x  = (const float*)d_in[0];
    const float* Wm = (const float*)d_in[1];
    float* y = (float*)d_out;

    const size_t ws_need = (size_t)(XT_TASKS + WT_TASKS) * 1024;  // ~21.8 MB
    if (ws_size >= ws_need) {
        prep_frag<<<(XT_TASKS + WT_TASKS) / 4, 256, 0, stream>>>(x, Wm, (uint32_t*)d_ws);
        gemm_pipe<<<(64 * 54) / 4, 256, 0, stream>>>((const uint32_t*)d_ws, y);
    } else {
        interp_fallback<<<NB * NS * NF * NTILES, 192, 0, stream>>>(x, Wm, y);
    }
}